// Round 10
// baseline (453.283 us; speedup 1.0000x reference)
//
#include <hip/hip_runtime.h>
#include <cmath>

// Match XLA/numpy non-fused mul+add rounding everywhere (IoU / decode bit-faithfulness).
#pragma clang fp contract(off)

namespace {
constexpr int NIMG = 8;
constexpr int NLVL = 5;
constexpr int LH[5]   = {208,104,52,26,13};
constexpr int LW[5]   = {336,168,84,42,21};
constexpr int LSTR[5] = {4,8,16,32,64};
constexpr int HWA[5]  = {209664,52416,13104,3276,819};
constexpr int KSEL[5] = {2000,2000,2000,2000,819};
constexpr int SOFF[5] = {0,2000,4000,6000,8000};
constexpr int MTOT    = 8819;
constexpr int CAP     = 6144;          // per-(img,lvl) candidate cap (expect <= ~2600)
constexpr int NPAIR   = NIMG*NLVL;     // 40
constexpr int CCUM[5] = {52,65,69,70,71};  // cumulative ceil(HWA/4096) per level
constexpr int BLK_PER_IMG = 71;
constexpr int MASK_W  = 32;            // u64 words per NMS mask row (covers 2048 cols)
constexpr int OUTK    = 1000;

// workspace byte offsets (all 16B-aligned where needed)
constexpr size_t OFF_HIST   = 0;              // 40*4096*4      = 655360
constexpr size_t OFF_PKC    = 0;              // 40*2048*4 = 327680, aliases hist (dead after k_scan)
constexpr size_t OFF_CNT    = 655360;         // 40*4           = 160
constexpr size_t OFF_THR    = 655520;         // 40*4           = 160
constexpr size_t ZERO_BYTES = 655680;         // memset range (hist+cnt+thr)
constexpr size_t OFF_CAND   = 655872;         // 40*6144*4      = 983040  -> 1638912
constexpr size_t OFF_SELIDX = 1638912;        // 8*8819*4       = 282208  -> 1921120
constexpr size_t OFF_SELKEY = 1921120;        // 8*8819*8       = 564416  -> 2485536
constexpr size_t OFF_SELSC  = 2485536;        // 8*8819*4       = 282208  -> 2767744
constexpr size_t OFF_SELBOX = 2767744;        // 8*8819*16      = 1128832 -> 3896576
constexpr size_t OFF_MASK   = 3896576;        // 40*2000*32*8   = 20480000-> 24376576
constexpr size_t OFF_CKEY   = OFF_MASK;       // 40*6144*8 = 1.97MB aliases maskbuf (dead by k_masks)
constexpr size_t OFF_KEEP   = 24376576;       // 40*32*8        = 10240   -> 24386816
}

struct Ins {
  const float* cls[5];
  const float* reg[5];
  const int* ih;
  const int* iw;
};

__device__ __forceinline__ void decode_block(int b, int& img, int& lvl, int& chunk) {
  img = b / BLK_PER_IMG;
  int rb = b - img*BLK_PER_IMG;
  if      (rb < CCUM[0]) { lvl=0; chunk=rb; }
  else if (rb < CCUM[1]) { lvl=1; chunk=rb-CCUM[0]; }
  else if (rb < CCUM[2]) { lvl=2; chunk=rb-CCUM[1]; }
  else if (rb < CCUM[3]) { lvl=3; chunk=rb-CCUM[2]; }
  else                   { lvl=4; chunk=0; }
}

// order-preserving float->u32 map (total order over floats)
__device__ __forceinline__ unsigned mapbits(float x) {
  unsigned u = __float_as_uint(x);
  return u ^ (unsigned)(((int)u >> 31) | (int)0x80000000);
}

// fp32 sigmoid with correctly-rounded exp step: matches 1/(1+exp_f32(-x)) pipeline
__device__ __forceinline__ float sigmoid_ref(float x) {
  float e = (float)exp(-(double)x);   // correctly-rounded f32 exp(-x)
  return 1.0f / (1.0f + e);           // exact-IEEE add + div
}

__device__ __forceinline__ unsigned long long readlane_u64(unsigned long long v, int lane) {
  unsigned lo = (unsigned)__builtin_amdgcn_readlane((int)(unsigned)v, lane);
  unsigned hi = (unsigned)__builtin_amdgcn_readlane((int)(unsigned)(v >> 32), lane);
  return ((unsigned long long)hi << 32) | (unsigned long long)lo;
}

// ---- K1: per-(img,lvl) 12-bit histogram of mapped logit bits ----
__global__ void k_hist(Ins in, unsigned* __restrict__ hist) {
  int img, lvl, chunk; decode_block(blockIdx.x, img, lvl, chunk);
  __shared__ unsigned lh[4096];
  for (int i = threadIdx.x; i < 4096; i += 256) lh[i] = 0;
  __syncthreads();
  const float* src = in.cls[lvl] + (size_t)img * HWA[lvl];
  int base = chunk * 4096;
  #pragma unroll
  for (int j = 0; j < 16; j++) {
    int e = base + j*256 + threadIdx.x;
    if (e < HWA[lvl]) {
      unsigned m = mapbits(src[e]);
      atomicAdd(&lh[m >> 20], 1u);
    }
  }
  __syncthreads();
  unsigned* gh = hist + (img*NLVL + lvl) * 4096;
  for (int i = threadIdx.x; i < 4096; i += 256)
    if (lh[i]) atomicAdd(&gh[i], lh[i]);
}

// ---- K2: find highest bin-edge with suffix count >= k ----
__global__ void k_scan(const unsigned* __restrict__ hist, unsigned* __restrict__ thr) {
  int pair = blockIdx.x; int lvl = pair % NLVL;
  const unsigned* h = hist + (size_t)pair * 4096;
  __shared__ unsigned part[256];
  unsigned s = 0;
  #pragma unroll
  for (int i = 0; i < 16; i++) s += h[threadIdx.x*16 + i];
  part[threadIdx.x] = s;
  __syncthreads();
  if (threadIdx.x == 0) {
    unsigned k = (unsigned)KSEL[lvl];
    unsigned cum = 0;
    unsigned edge = 0;
    for (int t = 255; t >= 0; t--) {
      if (cum + part[t] >= k) {
        for (int b = t*16 + 15; b >= t*16; b--) {
          cum += h[b];
          if (cum >= k) { edge = (unsigned)b; break; }
        }
        thr[pair] = edge << 20;
        return;
      }
      cum += part[t];
    }
    thr[pair] = 0u;
  }
}

// ---- K3: compact candidates; LDS block aggregation -> ONE global atomic/block ----
__global__ void __launch_bounds__(256) k_compact(Ins in, const unsigned* __restrict__ thr,
                          unsigned* __restrict__ cnt, unsigned* __restrict__ cand) {
  int img, lvl, chunk; decode_block(blockIdx.x, img, lvl, chunk);
  int pair = img*NLVL + lvl;
  unsigned T = thr[pair];
  const float* src = in.cls[lvl] + (size_t)img * HWA[lvl];
  int hw = LH[lvl] * LW[lvl];
  int base = chunk * 4096;
  int lid = threadIdx.x & 63;
  __shared__ unsigned lbuf[4096];      // block covers <=4096 elements: p always fits
  __shared__ unsigned lc, gbase;
  if (threadIdx.x == 0) lc = 0;
  __syncthreads();
  #pragma unroll
  for (int j = 0; j < 16; j++) {
    int e = base + j*256 + threadIdx.x;
    bool sel = (e < HWA[lvl]) && (mapbits(src[e]) >= T);
    unsigned long long mask = __ballot(sel);
    if (mask != 0ull) {
      int leader = __ffsll((long long)mask) - 1;
      unsigned wb = 0;
      if (lid == leader) wb = atomicAdd(&lc, (unsigned)__popcll(mask));  // LDS atomic
      wb = (unsigned)__shfl((int)wb, leader, 64);
      if (sel) {
        unsigned p = wb + (unsigned)__popcll(mask & ((1ull << lid) - 1ull));
        int a = e / hw;            // NCHW: e = a*hw + r
        int r = e - a*hw;
        lbuf[p] = (unsigned)(r*3 + a);  // score-space idx
      }
    }
  }
  __syncthreads();
  if (threadIdx.x == 0) gbase = atomicAdd(&cnt[pair], lc);  // one global atomic/block
  __syncthreads();
  unsigned nsel = lc, gb = gbase;
  for (unsigned t = threadIdx.x; t < nsel; t += 256) {
    unsigned p = gb + t;
    if (p < CAP) cand[(size_t)pair*CAP + p] = lbuf[t];      // coalesced
  }
}

// ---- K3b: compute sort keys ONCE per candidate (hoists dp-exp out of k_rank tiles) ----
__global__ void k_keys(Ins in, const unsigned* __restrict__ cntA,
                       const unsigned* __restrict__ cand,
                       unsigned long long* __restrict__ ckey) {
  int pair = blockIdx.y;
  int img = pair / NLVL, lvl = pair % NLVL;
  int c = min((int)cntA[pair], CAP);
  int j = blockIdx.x*256 + threadIdx.x;
  if (j >= c) return;
  unsigned idx = cand[(size_t)pair*CAP + j];
  int a = (int)(idx % 3u), r = (int)(idx / 3u);
  int hw = LH[lvl]*LW[lvl];
  float s = sigmoid_ref(in.cls[lvl][(size_t)img*HWA[lvl] + a*hw + r]);
  unsigned pack = ((unsigned)lvl << 18) | idx;   // < 2^21
  ckey[(size_t)pair*CAP + j] = ((unsigned long long)__float_as_uint(s) << 21)
                             | (unsigned long long)(0x1FFFFFu - pack);  // desc score, asc (lvl,idx)
}

// ---- K4: per-level exact rank (score desc, idx asc); scatter top-k into slots ----
__global__ void __launch_bounds__(256) k_rank(const unsigned* __restrict__ cntA,
                       const unsigned* __restrict__ cand,
                       const unsigned long long* __restrict__ ckey,
                       unsigned* __restrict__ sel_idx,
                       unsigned long long* __restrict__ sel_key,
                       float* __restrict__ sel_sc) {
  int pair = blockIdx.y; int tile = blockIdx.x;
  int img = pair / NLVL, lvl = pair % NLVL;
  int c = min((int)cntA[pair], CAP);
  if (tile*256 >= c) return;
  __shared__ unsigned long long keys[CAP];
  const unsigned long long* kp = ckey + (size_t)pair*CAP;
  for (int j = threadIdx.x; j < c; j += 256) keys[j] = kp[j];
  __syncthreads();
  int jj = tile*256 + threadIdx.x;
  if (jj >= c) return;
  unsigned long long mykey = keys[jj];
  int rk = 0;
  for (int j = 0; j < c; j++) rk += (keys[j] > mykey) ? 1 : 0;  // LDS broadcast
  if (rk < KSEL[lvl]) {
    int slot = img*MTOT + SOFF[lvl] + rk;
    sel_idx[slot] = cand[(size_t)pair*CAP + jj];
    sel_key[slot] = mykey;
    sel_sc[slot]  = __uint_as_float((unsigned)(mykey >> 21));
  }
}

// ---- K5: decode boxes (exact mmdet DeltaXYWH replication, clipped) ----
__global__ void k_decode(Ins in, const unsigned* __restrict__ sel_idx,
                         float* __restrict__ sel_box) {
  int t = blockIdx.x*256 + threadIdx.x;
  if (t >= NIMG*MTOT) return;
  int img = t / MTOT, pos = t - img*MTOT;
  int lvl = pos<2000?0 : pos<4000?1 : pos<6000?2 : pos<8000?3 : 4;
  unsigned idx = sel_idx[img*MTOT + pos];
  int a = (int)(idx % 3u);
  int r = (int)(idx / 3u);
  int Wl = LW[lvl]; int hw = LH[lvl]*Wl;
  int x = r % Wl, y = r / Wl;
  const float* rg = in.reg[lvl] + (size_t)img * 4 * HWA[lvl];  // 12*H*W
  float dx = rg[(a*4+0)*hw + r];
  float dy = rg[(a*4+1)*hw + r];
  float dw = rg[(a*4+2)*hw + r];
  float dh = rg[(a*4+3)*hw + r];
  float ratio = (a==0) ? 0.5f : (a==1) ? 1.0f : 2.0f;
  float hr = sqrtf(ratio);
  float wr = 1.0f / hr;
  float st = (float)LSTR[lvl];
  float wsz = st * wr * 8.0f;
  float hsz = st * hr * 8.0f;
  float xs = (float)x * st, ys = (float)y * st;
  float x1 = xs - wsz*0.5f, x2 = xs + wsz*0.5f;
  float y1 = ys - hsz*0.5f, y2 = ys + hsz*0.5f;
  float px = (x1 + x2) * 0.5f, py = (y1 + y2) * 0.5f;
  float pw = x2 - x1,          ph = y2 - y1;
  const float MR = 4.135166556742356f;
  dw = fminf(fmaxf(dw, -MR), MR);
  dh = fminf(fmaxf(dh, -MR), MR);
  float gx = px + pw*dx, gy = py + ph*dy;
  float gw = pw * (float)exp((double)dw);   // correctly-rounded f32 exp
  float gh = ph * (float)exp((double)dh);
  float Wi = (float)(*in.iw), Hi = (float)(*in.ih);
  float4 bb;
  bb.x = fminf(fmaxf(gx - gw*0.5f, 0.0f), Wi);
  bb.y = fminf(fmaxf(gy - gh*0.5f, 0.0f), Hi);
  bb.z = fminf(fmaxf(gx + gw*0.5f, 0.0f), Wi);
  bb.w = fminf(fmaxf(gy + gh*0.5f, 0.0f), Hi);
  ((float4*)sel_box)[img*MTOT + pos] = bb;
}

// ---- K6: NMS suppression-mask build — 256-row x 4-word tiles ----
// Row per lane; column boxes staged in 4KB LDS (broadcast reads, no conflicts).
// IoU decision WITHOUT the IEEE div in 99.999% of cases; rare ambiguous lanes
// take the exact f32 division. IoU on OFFSET boxes (+lvl*4096) bit-matches ref.
__global__ void __launch_bounds__(256) k_masks(const float* __restrict__ sel_box,
                        unsigned long long* __restrict__ maskbuf) {
  int pair = blockIdx.y; int lvl = pair % NLVL; int img = pair / NLVL;
  int n = KSEL[lvl];
  int nw = (n + 63) >> 6;
  int rblk = blockIdx.x >> 3;          // 0..7 (row tile of 256)
  int wg   = blockIdx.x & 7;           // 0..7 (word group of 4)
  int row0 = rblk * 256;
  int w0 = wg * 4, w1 = w0 + 4;
  if (row0 >= n) return;               // block-uniform exits (before barrier)
  if (w0 >= nw) return;
  if (w1 <= (row0 >> 6)) return;       // tile fully below diagonal
  __shared__ float4 bx[256];           // this tile's column boxes
  const float4* boxes = ((const float4*)sel_box) + img*MTOT + SOFF[lvl];
  float off = (float)lvl * 4096.0f;
  {
    int j = w0*64 + threadIdx.x;
    if (j < n) {
      float4 b = boxes[j];
      b.x += off; b.y += off; b.z += off; b.w += off;
      bx[threadIdx.x] = b;
    }
  }
  __syncthreads();
  int i = row0 + threadIdx.x;          // row per lane
  bool act = (i < n);
  float4 bi = make_float4(0.f, 0.f, 0.f, 0.f);
  float ai = 0.f;
  if (act) {
    bi = boxes[i];
    bi.x += off; bi.y += off; bi.z += off; bi.w += off;
    ai = (bi.z - bi.x) * (bi.w - bi.y);
  }
  int ws = (row0 + (threadIdx.x & ~63)) >> 6;   // wave-uniform: == i>>6 for all lanes
  int jw_lo = max(w0, ws);
  int jw_hi = min(w1, nw);
  unsigned long long* mrow = maskbuf + (size_t)pair*2000*MASK_W + (size_t)i*MASK_W;
  for (int jw = jw_lo; jw < jw_hi; jw++) {
    int jbase = jw * 64;
    int lbase = (jw - w0) * 64;
    int bmax = min(64, n - jbase);
    unsigned long long wbits = 0ull;
    #pragma unroll 4
    for (int b = 0; b < bmax; b++) {
      float4 bj = bx[lbase + b];       // LDS broadcast (uniform address)
      float aj = (bj.z - bj.x) * (bj.w - bj.y);
      float xx1 = fmaxf(bi.x, bj.x), yy1 = fmaxf(bi.y, bj.y);
      float xx2 = fminf(bi.z, bj.z), yy2 = fminf(bi.w, bj.w);
      float iw_ = fmaxf(xx2 - xx1, 0.0f), ih_ = fmaxf(yy2 - yy1, 0.0f);
      float inter = iw_ * ih_;
      float uni = fmaxf(ai + aj - inter, 1e-6f);
      float prod = 0.7f * uni;
      float diff = inter - prod;
      bool sup;
      if (fabsf(diff) <= prod * 3.8e-6f) {
        sup = (inter / uni) > 0.7f;    // rare exact path (exec-masked, usually skipped)
      } else {
        sup = diff > 0.0f;
      }
      sup = sup && (jbase + b > i);
      wbits |= ((unsigned long long)sup) << b;
    }
    if (act) mrow[jw] = wbits;
  }
}

// ---- K7: block-diagonal greedy NMS — producer/consumer wave pair ----
// Wave 1 (producer) stages block k+1's 64 contiguous mask rows (16KB) into a
// double-buffered LDS region with coalesced float4 loads: its vmcnt drain
// overlaps wave 0's compute. Wave 0 (consumer) runs the r9 block-diagonal
// greedy (register triangle via readlane) reading rows from LDS (~120cyc
// lgkm drain instead of ~900cyc global). Barrier-pipelined, buffers disjoint.
__global__ void __launch_bounds__(128, 1) k_nms(const unsigned long long* __restrict__ maskbuf,
                      unsigned long long* __restrict__ keep) {
  int pair = blockIdx.x; int lvl = pair % NLVL;
  int n = KSEL[lvl];
  int nw = (n + 63) >> 6;
  int tid = threadIdx.x;
  bool consumer = (tid < 64);
  int lane = tid & 63;
  int w = lane & 31;                   // word index this lane owns
  int h = lane >> 5;                   // row-half within 64-row block
  const unsigned long long* mrow = maskbuf + (size_t)pair*2000*MASK_W;
  __shared__ unsigned long long sbuf[2][64*MASK_W];   // 2 x 16KB

  // stage block kk's rows 64kk..64kk+63 (clamped to pair's 2000-row region)
  auto stage = [&](int kk) {
    const float4* src = (const float4*)(mrow + (size_t)(64*kk)*MASK_W);
    float4* dst = (float4*)sbuf[kk & 1];
    int cmax = (2000 - 64*kk) >> 2;    // 4 rows per 1KB chunk
    if (cmax > 16) cmax = 16;
    #pragma unroll
    for (int c = 0; c < 16; c++) {
      if (c < cmax) dst[c*64 + lane] = src[c*64 + lane];
    }
  };

  if (!consumer) stage(0);
  __syncthreads();

  unsigned long long rem = 0ull;       // lane (w,h): suppression word w from rows half h
  unsigned long long frozen = ~0ull;   // final suppressed mask for word w (set at k==w)
  unsigned long long R[32];

  for (int k = 0; k < nw; k++) {
    if (!consumer) {
      if (k + 1 < nw) stage(k + 1);    // writes sbuf[(k+1)&1] — disjoint from consumer
    } else {
      const unsigned long long* lb = sbuf[k & 1];
      #pragma unroll
      for (int i = 0; i < 32; i++)
        R[i] = lb[(h*32 + i)*MASK_W + w];        // conflict-free ds_read_b64
      unsigned long long S = readlane_u64(rem, k) | readlane_u64(rem, k + 32);
      int nb = n - 64*k; if (nb > 64) nb = 64;   // valid boxes in this block
      #pragma unroll
      for (int b = 0; b < 64; b++) {
        int src = (b < 32) ? k : k + 32;         // lane holding word k of block-row b
        unsigned long long m = readlane_u64(R[b & 31], src);
        bool use = (b < nb) && !((S >> b) & 1ull);
        S |= use ? m : 0ull;
      }
      if (lane == k) frozen = S;
      if (w > k) {
        int rbase = 64*k + h*32;
        #pragma unroll
        for (int i = 0; i < 32; i++) {
          int row = rbase + i;
          bool alive = (row < n) && !((S >> (h*32 + i)) & 1ull);
          rem |= alive ? R[i] : 0ull;
        }
      }
    }
    __syncthreads();
  }
  if (tid < MASK_W)
    keep[(size_t)pair*MASK_W + tid] = ~frozen;
}

// ---- K7b: inclusive prefix-count of kept per (img,lvl) position ----
__global__ void __launch_bounds__(64) k_pfx(const unsigned long long* __restrict__ keep,
                                            int* __restrict__ pkc) {
  int pair = blockIdx.x; int lvl = pair % NLVL;
  int n = KSEL[lvl];
  int nw = (n + 63) >> 6;
  int lane = threadIdx.x;
  unsigned long long w = (lane < nw) ? keep[(size_t)pair*MASK_W + lane] : 0ull;
  if (lane == nw - 1 && (n & 63)) w &= (1ull << (n & 63)) - 1ull;  // bits >= n are garbage
  __shared__ int lcnt[64];
  lcnt[lane] = __popcll(w);
  __syncthreads();
  int pre = 0;
  for (int t = 0; t < lane; t++) pre += lcnt[t];   // <=63 LDS adds, one wave — fine
  for (int b = 0; b < 64; b++) {
    int p = lane*64 + b;
    if (p < n) {
      pre += (int)((w >> b) & 1ull);
      pkc[pair*2048 + p] = pre;
    }
  }
}

// ---- K8: rank kept boxes via per-level prefix counts + 4 binary searches ----
__global__ void __launch_bounds__(256) k_out2(const unsigned long long* __restrict__ sel_key,
                      const float* __restrict__ sel_box,
                      const unsigned long long* __restrict__ keep,
                      const int* __restrict__ pkc,
                      float* __restrict__ out) {
  int img = blockIdx.y;
  int pos = blockIdx.x*256 + threadIdx.x;
  if (pos >= MTOT) return;
  int lvl = pos<2000?0 : pos<4000?1 : pos<6000?2 : pos<8000?3 : 4;
  int local = pos - SOFF[lvl];
  int pair = img*NLVL + lvl;
  unsigned long long kw = keep[(size_t)pair*MASK_W + (local >> 6)];
  if (!((kw >> (local & 63)) & 1ull)) return;
  unsigned long long mykey = sel_key[img*MTOT + pos];
  int rank = pkc[pair*2048 + local] - 1;    // kept before me within my level
  #pragma unroll
  for (int l2 = 0; l2 < NLVL; l2++) {
    if (l2 == lvl) continue;
    const unsigned long long* A = sel_key + img*MTOT + SOFF[l2];
    int lo = 0, hi = KSEL[l2];
    while (lo < hi) {
      int mid = (lo + hi) >> 1;
      if (A[mid] > mykey) lo = mid + 1; else hi = mid;
    }
    if (lo > 0) rank += pkc[(img*NLVL + l2)*2048 + lo - 1];
  }
  if (rank < OUTK) {
    ((float4*)out)[img*OUTK + rank] = ((const float4*)sel_box)[img*MTOT + pos];
    out[NIMG*OUTK*4 + img*OUTK + rank] = __uint_as_float((unsigned)(mykey >> 21));
  }
}

extern "C" void kernel_launch(void* const* d_in, const int* in_sizes, int n_in,
                              void* d_out, int out_size, void* d_ws, size_t ws_size,
                              hipStream_t stream) {
  Ins in;
  // setup_inputs dict order: cls_0, reg_0, cls_1, reg_1, ..., cls_4, reg_4, image_h, image_w
  for (int l = 0; l < 5; l++) {
    in.cls[l] = (const float*)d_in[2*l];
    in.reg[l] = (const float*)d_in[2*l + 1];
  }
  in.ih = (const int*)d_in[10];
  in.iw = (const int*)d_in[11];

  char* ws = (char*)d_ws;
  unsigned* hist              = (unsigned*)(ws + OFF_HIST);
  int* pkc                    = (int*)(ws + OFF_PKC);          // aliases hist (dead after k_scan)
  unsigned* cnt               = (unsigned*)(ws + OFF_CNT);
  unsigned* thr               = (unsigned*)(ws + OFF_THR);
  unsigned* cand              = (unsigned*)(ws + OFF_CAND);
  unsigned* sel_idx           = (unsigned*)(ws + OFF_SELIDX);
  unsigned long long* sel_key = (unsigned long long*)(ws + OFF_SELKEY);
  float* sel_sc               = (float*)(ws + OFF_SELSC);
  float* sel_box              = (float*)(ws + OFF_SELBOX);
  unsigned long long* maskbuf = (unsigned long long*)(ws + OFF_MASK);
  unsigned long long* ckey    = (unsigned long long*)(ws + OFF_CKEY);  // aliases maskbuf (dead before k_masks)
  unsigned long long* keep    = (unsigned long long*)(ws + OFF_KEEP);
  float* out                  = (float*)d_out;

  hipMemsetAsync(d_ws, 0, ZERO_BYTES, stream);                 // hist + counters + thr
  hipMemsetAsync(d_out, 0, (size_t)NIMG*OUTK*5*sizeof(float), stream); // zero-padded outputs

  k_hist   <<<NIMG*BLK_PER_IMG, 256, 0, stream>>>(in, hist);
  k_scan   <<<NPAIR, 256, 0, stream>>>(hist, thr);
  k_compact<<<NIMG*BLK_PER_IMG, 256, 0, stream>>>(in, thr, cnt, cand);
  k_keys   <<<dim3(CAP/256, NPAIR), 256, 0, stream>>>(in, cnt, cand, ckey);
  k_rank   <<<dim3(CAP/256, NPAIR), 256, 0, stream>>>(cnt, cand, ckey, sel_idx, sel_key, sel_sc);
  k_decode <<<(NIMG*MTOT + 255)/256, 256, 0, stream>>>(in, sel_idx, sel_box);
  k_masks  <<<dim3(64, NPAIR), 256, 0, stream>>>(sel_box, maskbuf);
  k_nms    <<<NPAIR, 128, 0, stream>>>(maskbuf, keep);
  k_pfx    <<<NPAIR, 64, 0, stream>>>(keep, pkc);
  k_out2   <<<dim3((MTOT + 255)/256, NIMG), 256, 0, stream>>>(sel_key, sel_box, keep, pkc, out);
}

// Round 11
// 403.694 us; speedup vs baseline: 1.1228x; 1.1228x over previous
//
#include <hip/hip_runtime.h>
#include <cmath>

// Match XLA/numpy non-fused mul+add rounding everywhere (IoU / decode bit-faithfulness).
#pragma clang fp contract(off)

namespace {
constexpr int NIMG = 8;
constexpr int NLVL = 5;
constexpr int LH[5]   = {208,104,52,26,13};
constexpr int LW[5]   = {336,168,84,42,21};
constexpr int LSTR[5] = {4,8,16,32,64};
constexpr int HWA[5]  = {209664,52416,13104,3276,819};
constexpr int KSEL[5] = {2000,2000,2000,2000,819};
constexpr int SOFF[5] = {0,2000,4000,6000,8000};
constexpr int MTOT    = 8819;
constexpr int CAP     = 6144;          // per-(img,lvl) candidate cap (expect <= ~2600)
constexpr int NPAIR   = NIMG*NLVL;     // 40
constexpr int CCUM[5] = {52,65,69,70,71};  // cumulative ceil(HWA/4096) per level
constexpr int BLK_PER_IMG = 71;
constexpr int MASK_W  = 32;            // u64 words per NMS mask row (covers 2048 cols)
constexpr int OUTK    = 1000;

// workspace byte offsets (all 16B-aligned where needed)
constexpr size_t OFF_HIST   = 0;              // 40*4096*4      = 655360
constexpr size_t OFF_PKC    = 0;              // 40*2048*4 = 327680, aliases hist (dead after k_scan)
constexpr size_t OFF_CNT    = 655360;         // 40*4           = 160
constexpr size_t OFF_THR    = 655520;         // 40*4           = 160
constexpr size_t ZERO_BYTES = 655680;         // memset range (hist+cnt+thr)
constexpr size_t OFF_CAND   = 655872;         // 40*6144*4      = 983040  -> 1638912
constexpr size_t OFF_SELIDX = 1638912;        // 8*8819*4       = 282208  -> 1921120
constexpr size_t OFF_SELKEY = 1921120;        // 8*8819*8       = 564416  -> 2485536
constexpr size_t OFF_SELSC  = 2485536;        // 8*8819*4       = 282208  -> 2767744
constexpr size_t OFF_SELBOX = 2767744;        // 8*8819*16      = 1128832 -> 3896576
constexpr size_t OFF_MASK   = 3896576;        // 40*2000*32*8   = 20480000-> 24376576
constexpr size_t OFF_CKEY   = OFF_MASK;       // 40*6144*8 = 1.97MB aliases maskbuf (dead by k_masks)
constexpr size_t OFF_KEEP   = 24376576;       // 40*32*8        = 10240   -> 24386816
}

struct Ins {
  const float* cls[5];
  const float* reg[5];
  const int* ih;
  const int* iw;
};

__device__ __forceinline__ void decode_block(int b, int& img, int& lvl, int& chunk) {
  img = b / BLK_PER_IMG;
  int rb = b - img*BLK_PER_IMG;
  if      (rb < CCUM[0]) { lvl=0; chunk=rb; }
  else if (rb < CCUM[1]) { lvl=1; chunk=rb-CCUM[0]; }
  else if (rb < CCUM[2]) { lvl=2; chunk=rb-CCUM[1]; }
  else if (rb < CCUM[3]) { lvl=3; chunk=rb-CCUM[2]; }
  else                   { lvl=4; chunk=0; }
}

// order-preserving float->u32 map (total order over floats)
__device__ __forceinline__ unsigned mapbits(float x) {
  unsigned u = __float_as_uint(x);
  return u ^ (unsigned)(((int)u >> 31) | (int)0x80000000);
}

// fp32 sigmoid with correctly-rounded exp step: matches 1/(1+exp_f32(-x)) pipeline
__device__ __forceinline__ float sigmoid_ref(float x) {
  float e = (float)exp(-(double)x);   // correctly-rounded f32 exp(-x)
  return 1.0f / (1.0f + e);           // exact-IEEE add + div
}

__device__ __forceinline__ unsigned long long readlane_u64(unsigned long long v, int lane) {
  unsigned lo = (unsigned)__builtin_amdgcn_readlane((int)(unsigned)v, lane);
  unsigned hi = (unsigned)__builtin_amdgcn_readlane((int)(unsigned)(v >> 32), lane);
  return ((unsigned long long)hi << 32) | (unsigned long long)lo;
}

// ---- K1: per-(img,lvl) 12-bit histogram of mapped logit bits ----
__global__ void k_hist(Ins in, unsigned* __restrict__ hist) {
  int img, lvl, chunk; decode_block(blockIdx.x, img, lvl, chunk);
  __shared__ unsigned lh[4096];
  for (int i = threadIdx.x; i < 4096; i += 256) lh[i] = 0;
  __syncthreads();
  const float* src = in.cls[lvl] + (size_t)img * HWA[lvl];
  int base = chunk * 4096;
  #pragma unroll
  for (int j = 0; j < 16; j++) {
    int e = base + j*256 + threadIdx.x;
    if (e < HWA[lvl]) {
      unsigned m = mapbits(src[e]);
      atomicAdd(&lh[m >> 20], 1u);
    }
  }
  __syncthreads();
  unsigned* gh = hist + (img*NLVL + lvl) * 4096;
  for (int i = threadIdx.x; i < 4096; i += 256)
    if (lh[i]) atomicAdd(&gh[i], lh[i]);
}

// ---- K2: find highest bin-edge with suffix count >= k ----
__global__ void k_scan(const unsigned* __restrict__ hist, unsigned* __restrict__ thr) {
  int pair = blockIdx.x; int lvl = pair % NLVL;
  const unsigned* h = hist + (size_t)pair * 4096;
  __shared__ unsigned part[256];
  unsigned s = 0;
  #pragma unroll
  for (int i = 0; i < 16; i++) s += h[threadIdx.x*16 + i];
  part[threadIdx.x] = s;
  __syncthreads();
  if (threadIdx.x == 0) {
    unsigned k = (unsigned)KSEL[lvl];
    unsigned cum = 0;
    unsigned edge = 0;
    for (int t = 255; t >= 0; t--) {
      if (cum + part[t] >= k) {
        for (int b = t*16 + 15; b >= t*16; b--) {
          cum += h[b];
          if (cum >= k) { edge = (unsigned)b; break; }
        }
        thr[pair] = edge << 20;
        return;
      }
      cum += part[t];
    }
    thr[pair] = 0u;
  }
}

// ---- K3: compact candidates; LDS block aggregation -> ONE global atomic/block ----
__global__ void __launch_bounds__(256) k_compact(Ins in, const unsigned* __restrict__ thr,
                          unsigned* __restrict__ cnt, unsigned* __restrict__ cand) {
  int img, lvl, chunk; decode_block(blockIdx.x, img, lvl, chunk);
  int pair = img*NLVL + lvl;
  unsigned T = thr[pair];
  const float* src = in.cls[lvl] + (size_t)img * HWA[lvl];
  int hw = LH[lvl] * LW[lvl];
  int base = chunk * 4096;
  int lid = threadIdx.x & 63;
  __shared__ unsigned lbuf[4096];      // block covers <=4096 elements: p always fits
  __shared__ unsigned lc, gbase;
  if (threadIdx.x == 0) lc = 0;
  __syncthreads();
  #pragma unroll
  for (int j = 0; j < 16; j++) {
    int e = base + j*256 + threadIdx.x;
    bool sel = (e < HWA[lvl]) && (mapbits(src[e]) >= T);
    unsigned long long mask = __ballot(sel);
    if (mask != 0ull) {
      int leader = __ffsll((long long)mask) - 1;
      unsigned wb = 0;
      if (lid == leader) wb = atomicAdd(&lc, (unsigned)__popcll(mask));  // LDS atomic
      wb = (unsigned)__shfl((int)wb, leader, 64);
      if (sel) {
        unsigned p = wb + (unsigned)__popcll(mask & ((1ull << lid) - 1ull));
        int a = e / hw;            // NCHW: e = a*hw + r
        int r = e - a*hw;
        lbuf[p] = (unsigned)(r*3 + a);  // score-space idx
      }
    }
  }
  __syncthreads();
  if (threadIdx.x == 0) gbase = atomicAdd(&cnt[pair], lc);  // one global atomic/block
  __syncthreads();
  unsigned nsel = lc, gb = gbase;
  for (unsigned t = threadIdx.x; t < nsel; t += 256) {
    unsigned p = gb + t;
    if (p < CAP) cand[(size_t)pair*CAP + p] = lbuf[t];      // coalesced
  }
}

// ---- K3b: compute sort keys ONCE per candidate (hoists dp-exp out of k_rank tiles) ----
__global__ void k_keys(Ins in, const unsigned* __restrict__ cntA,
                       const unsigned* __restrict__ cand,
                       unsigned long long* __restrict__ ckey) {
  int pair = blockIdx.y;
  int img = pair / NLVL, lvl = pair % NLVL;
  int c = min((int)cntA[pair], CAP);
  int j = blockIdx.x*256 + threadIdx.x;
  if (j >= c) return;
  unsigned idx = cand[(size_t)pair*CAP + j];
  int a = (int)(idx % 3u), r = (int)(idx / 3u);
  int hw = LH[lvl]*LW[lvl];
  float s = sigmoid_ref(in.cls[lvl][(size_t)img*HWA[lvl] + a*hw + r]);
  unsigned pack = ((unsigned)lvl << 18) | idx;   // < 2^21
  ckey[(size_t)pair*CAP + j] = ((unsigned long long)__float_as_uint(s) << 21)
                             | (unsigned long long)(0x1FFFFFu - pack);  // desc score, asc (lvl,idx)
}

// ---- K4: per-level exact rank (score desc, idx asc); scatter top-k into slots ----
__global__ void __launch_bounds__(256) k_rank(const unsigned* __restrict__ cntA,
                       const unsigned* __restrict__ cand,
                       const unsigned long long* __restrict__ ckey,
                       unsigned* __restrict__ sel_idx,
                       unsigned long long* __restrict__ sel_key,
                       float* __restrict__ sel_sc) {
  int pair = blockIdx.y; int tile = blockIdx.x;
  int img = pair / NLVL, lvl = pair % NLVL;
  int c = min((int)cntA[pair], CAP);
  if (tile*256 >= c) return;
  __shared__ unsigned long long keys[CAP];
  const unsigned long long* kp = ckey + (size_t)pair*CAP;
  for (int j = threadIdx.x; j < c; j += 256) keys[j] = kp[j];
  __syncthreads();
  int jj = tile*256 + threadIdx.x;
  if (jj >= c) return;
  unsigned long long mykey = keys[jj];
  int rk = 0;
  for (int j = 0; j < c; j++) rk += (keys[j] > mykey) ? 1 : 0;  // LDS broadcast
  if (rk < KSEL[lvl]) {
    int slot = img*MTOT + SOFF[lvl] + rk;
    sel_idx[slot] = cand[(size_t)pair*CAP + jj];
    sel_key[slot] = mykey;
    sel_sc[slot]  = __uint_as_float((unsigned)(mykey >> 21));
  }
}

// ---- K5: decode boxes (exact mmdet DeltaXYWH replication, clipped) ----
__global__ void k_decode(Ins in, const unsigned* __restrict__ sel_idx,
                         float* __restrict__ sel_box) {
  int t = blockIdx.x*256 + threadIdx.x;
  if (t >= NIMG*MTOT) return;
  int img = t / MTOT, pos = t - img*MTOT;
  int lvl = pos<2000?0 : pos<4000?1 : pos<6000?2 : pos<8000?3 : 4;
  unsigned idx = sel_idx[img*MTOT + pos];
  int a = (int)(idx % 3u);
  int r = (int)(idx / 3u);
  int Wl = LW[lvl]; int hw = LH[lvl]*Wl;
  int x = r % Wl, y = r / Wl;
  const float* rg = in.reg[lvl] + (size_t)img * 4 * HWA[lvl];  // 12*H*W
  float dx = rg[(a*4+0)*hw + r];
  float dy = rg[(a*4+1)*hw + r];
  float dw = rg[(a*4+2)*hw + r];
  float dh = rg[(a*4+3)*hw + r];
  float ratio = (a==0) ? 0.5f : (a==1) ? 1.0f : 2.0f;
  float hr = sqrtf(ratio);
  float wr = 1.0f / hr;
  float st = (float)LSTR[lvl];
  float wsz = st * wr * 8.0f;
  float hsz = st * hr * 8.0f;
  float xs = (float)x * st, ys = (float)y * st;
  float x1 = xs - wsz*0.5f, x2 = xs + wsz*0.5f;
  float y1 = ys - hsz*0.5f, y2 = ys + hsz*0.5f;
  float px = (x1 + x2) * 0.5f, py = (y1 + y2) * 0.5f;
  float pw = x2 - x1,          ph = y2 - y1;
  const float MR = 4.135166556742356f;
  dw = fminf(fmaxf(dw, -MR), MR);
  dh = fminf(fmaxf(dh, -MR), MR);
  float gx = px + pw*dx, gy = py + ph*dy;
  float gw = pw * (float)exp((double)dw);   // correctly-rounded f32 exp
  float gh = ph * (float)exp((double)dh);
  float Wi = (float)(*in.iw), Hi = (float)(*in.ih);
  float4 bb;
  bb.x = fminf(fmaxf(gx - gw*0.5f, 0.0f), Wi);
  bb.y = fminf(fmaxf(gy - gh*0.5f, 0.0f), Hi);
  bb.z = fminf(fmaxf(gx + gw*0.5f, 0.0f), Wi);
  bb.w = fminf(fmaxf(gy + gh*0.5f, 0.0f), Hi);
  ((float4*)sel_box)[img*MTOT + pos] = bb;
}

// ---- K6: NMS suppression-mask build — 256-row x 4-word tiles ----
// Row per lane; column boxes staged in 4KB LDS (broadcast reads, no conflicts).
// IoU decision WITHOUT the IEEE div in 99.999% of cases; rare ambiguous lanes
// take the exact f32 division. IoU on OFFSET boxes (+lvl*4096) bit-matches ref.
__global__ void __launch_bounds__(256) k_masks(const float* __restrict__ sel_box,
                        unsigned long long* __restrict__ maskbuf) {
  int pair = blockIdx.y; int lvl = pair % NLVL; int img = pair / NLVL;
  int n = KSEL[lvl];
  int nw = (n + 63) >> 6;
  int rblk = blockIdx.x >> 3;          // 0..7 (row tile of 256)
  int wg   = blockIdx.x & 7;           // 0..7 (word group of 4)
  int row0 = rblk * 256;
  int w0 = wg * 4, w1 = w0 + 4;
  if (row0 >= n) return;               // block-uniform exits (before barrier)
  if (w0 >= nw) return;
  if (w1 <= (row0 >> 6)) return;       // tile fully below diagonal
  __shared__ float4 bx[256];           // this tile's column boxes
  const float4* boxes = ((const float4*)sel_box) + img*MTOT + SOFF[lvl];
  float off = (float)lvl * 4096.0f;
  {
    int j = w0*64 + threadIdx.x;
    if (j < n) {
      float4 b = boxes[j];
      b.x += off; b.y += off; b.z += off; b.w += off;
      bx[threadIdx.x] = b;
    }
  }
  __syncthreads();
  int i = row0 + threadIdx.x;          // row per lane
  bool act = (i < n);
  float4 bi = make_float4(0.f, 0.f, 0.f, 0.f);
  float ai = 0.f;
  if (act) {
    bi = boxes[i];
    bi.x += off; bi.y += off; bi.z += off; bi.w += off;
    ai = (bi.z - bi.x) * (bi.w - bi.y);
  }
  int ws = (row0 + (threadIdx.x & ~63)) >> 6;   // wave-uniform: == i>>6 for all lanes
  int jw_lo = max(w0, ws);
  int jw_hi = min(w1, nw);
  unsigned long long* mrow = maskbuf + (size_t)pair*2000*MASK_W + (size_t)i*MASK_W;
  for (int jw = jw_lo; jw < jw_hi; jw++) {
    int jbase = jw * 64;
    int lbase = (jw - w0) * 64;
    int bmax = min(64, n - jbase);
    unsigned long long wbits = 0ull;
    #pragma unroll 4
    for (int b = 0; b < bmax; b++) {
      float4 bj = bx[lbase + b];       // LDS broadcast (uniform address)
      float aj = (bj.z - bj.x) * (bj.w - bj.y);
      float xx1 = fmaxf(bi.x, bj.x), yy1 = fmaxf(bi.y, bj.y);
      float xx2 = fminf(bi.z, bj.z), yy2 = fminf(bi.w, bj.w);
      float iw_ = fmaxf(xx2 - xx1, 0.0f), ih_ = fmaxf(yy2 - yy1, 0.0f);
      float inter = iw_ * ih_;
      float uni = fmaxf(ai + aj - inter, 1e-6f);
      float prod = 0.7f * uni;
      float diff = inter - prod;
      bool sup;
      if (fabsf(diff) <= prod * 3.8e-6f) {
        sup = (inter / uni) > 0.7f;    // rare exact path (exec-masked, usually skipped)
      } else {
        sup = diff > 0.0f;
      }
      sup = sup && (jbase + b > i);
      wbits |= ((unsigned long long)sup) << b;
    }
    if (act) mrow[jw] = wbits;
  }
}

// ---- K7: block-diagonal greedy NMS (one wave per (img,lvl)) ----
// Anti-sinking structure: UNCONDITIONAL straight-line clamped loads (first use
// is a batched readlane hoist, so load-sinking == batching). In-block 64x64
// matrix is hoisted to UNIFORM (SGPR) values in 4 chunks of 16 rows; the serial
// greedy chain is then pure scalar ops on S. Accumulate uses a per-lane 32-bit
// half of S so each row test is ~5 VALU. No barriers, no producer wave.
__global__ void __launch_bounds__(64, 1) k_nms(const unsigned long long* __restrict__ maskbuf,
                      unsigned long long* __restrict__ keep) {
  int pair = blockIdx.x; int lvl = pair % NLVL;
  int n = KSEL[lvl];
  int nw = (n + 63) >> 6;
  int lane = threadIdx.x;
  int w = lane & 31;                   // word index this lane owns
  int h = lane >> 5;                   // row-half: rows h*32..h*32+31 of each block
  const unsigned long long* mrow = maskbuf + (size_t)pair*2000*MASK_W;
  unsigned long long rem = 0ull;       // lane (w,h): suppression word w from rows half h
  unsigned long long frozen = ~0ull;   // final suppressed mask for word w (set at k==w)
  unsigned long long R[32];

  for (int k = 0; k < nw; k++) {
    int rbase = 64*k + h*32;
    // ---- batch load: word w of this block's rows (UNconditional, clamped) ----
    #pragma unroll
    for (int i = 0; i < 32; i++) {
      int row = rbase + i;
      if (row > n - 1) row = n - 1;    // clamp: always a valid allocated row
      R[i] = mrow[(size_t)row*MASK_W + w];
    }
    int nb = n - 64*k; if (nb > 64) nb = 64;   // valid boxes in this block
    unsigned long long S = readlane_u64(rem, k) | readlane_u64(rem, k + 32);
    // ---- triangle: 4 chunks of 16 rows; hoist to uniforms, then SALU chain ----
    #pragma unroll
    for (int c = 0; c < 4; c++) {
      int src = (c < 2) ? k : k + 32;  // lane holding word k of these block-rows
      unsigned long long M[16];
      #pragma unroll
      for (int i = 0; i < 16; i++) {
        int b = c*16 + i;
        unsigned long long m = readlane_u64(R[(c & 1)*16 + i], src);
        M[i] = (b < nb) ? m : 0ull;    // off critical path
      }
      #pragma unroll
      for (int i = 0; i < 16; i++) {
        int b = c*16 + i;
        S |= ((S >> b) & 1ull) ? 0ull : M[i];   // ~5 scalar ops, b constexpr
      }
    }
    if (lane == k) frozen = S;
    // ---- accumulate alive rows' suppression into later words (lanes w>k) ----
    if (w > k) {
      unsigned Sh = (unsigned)(h ? (S >> 32) : S);   // per-lane half of S
      #pragma unroll
      for (int i = 0; i < 32; i++) {
        int row = rbase + i;
        bool alive = (row < n) && !((Sh >> i) & 1u);
        rem |= alive ? R[i] : 0ull;
      }
    }
  }
  if (lane < MASK_W)
    keep[(size_t)pair*MASK_W + lane] = ~frozen;
}

// ---- K7b: inclusive prefix-count of kept per (img,lvl) position ----
__global__ void __launch_bounds__(64) k_pfx(const unsigned long long* __restrict__ keep,
                                            int* __restrict__ pkc) {
  int pair = blockIdx.x; int lvl = pair % NLVL;
  int n = KSEL[lvl];
  int nw = (n + 63) >> 6;
  int lane = threadIdx.x;
  unsigned long long w = (lane < nw) ? keep[(size_t)pair*MASK_W + lane] : 0ull;
  if (lane == nw - 1 && (n & 63)) w &= (1ull << (n & 63)) - 1ull;  // bits >= n are garbage
  __shared__ int lcnt[64];
  lcnt[lane] = __popcll(w);
  __syncthreads();
  int pre = 0;
  for (int t = 0; t < lane; t++) pre += lcnt[t];   // <=63 LDS adds, one wave — fine
  for (int b = 0; b < 64; b++) {
    int p = lane*64 + b;
    if (p < n) {
      pre += (int)((w >> b) & 1ull);
      pkc[pair*2048 + p] = pre;
    }
  }
}

// ---- K8: rank kept boxes via per-level prefix counts + 4 binary searches ----
__global__ void __launch_bounds__(256) k_out2(const unsigned long long* __restrict__ sel_key,
                      const float* __restrict__ sel_box,
                      const unsigned long long* __restrict__ keep,
                      const int* __restrict__ pkc,
                      float* __restrict__ out) {
  int img = blockIdx.y;
  int pos = blockIdx.x*256 + threadIdx.x;
  if (pos >= MTOT) return;
  int lvl = pos<2000?0 : pos<4000?1 : pos<6000?2 : pos<8000?3 : 4;
  int local = pos - SOFF[lvl];
  int pair = img*NLVL + lvl;
  unsigned long long kw = keep[(size_t)pair*MASK_W + (local >> 6)];
  if (!((kw >> (local & 63)) & 1ull)) return;
  unsigned long long mykey = sel_key[img*MTOT + pos];
  int rank = pkc[pair*2048 + local] - 1;    // kept before me within my level
  #pragma unroll
  for (int l2 = 0; l2 < NLVL; l2++) {
    if (l2 == lvl) continue;
    const unsigned long long* A = sel_key + img*MTOT + SOFF[l2];
    int lo = 0, hi = KSEL[l2];
    while (lo < hi) {
      int mid = (lo + hi) >> 1;
      if (A[mid] > mykey) lo = mid + 1; else hi = mid;
    }
    if (lo > 0) rank += pkc[(img*NLVL + l2)*2048 + lo - 1];
  }
  if (rank < OUTK) {
    ((float4*)out)[img*OUTK + rank] = ((const float4*)sel_box)[img*MTOT + pos];
    out[NIMG*OUTK*4 + img*OUTK + rank] = __uint_as_float((unsigned)(mykey >> 21));
  }
}

extern "C" void kernel_launch(void* const* d_in, const int* in_sizes, int n_in,
                              void* d_out, int out_size, void* d_ws, size_t ws_size,
                              hipStream_t stream) {
  Ins in;
  // setup_inputs dict order: cls_0, reg_0, cls_1, reg_1, ..., cls_4, reg_4, image_h, image_w
  for (int l = 0; l < 5; l++) {
    in.cls[l] = (const float*)d_in[2*l];
    in.reg[l] = (const float*)d_in[2*l + 1];
  }
  in.ih = (const int*)d_in[10];
  in.iw = (const int*)d_in[11];

  char* ws = (char*)d_ws;
  unsigned* hist              = (unsigned*)(ws + OFF_HIST);
  int* pkc                    = (int*)(ws + OFF_PKC);          // aliases hist (dead after k_scan)
  unsigned* cnt               = (unsigned*)(ws + OFF_CNT);
  unsigned* thr               = (unsigned*)(ws + OFF_THR);
  unsigned* cand              = (unsigned*)(ws + OFF_CAND);
  unsigned* sel_idx           = (unsigned*)(ws + OFF_SELIDX);
  unsigned long long* sel_key = (unsigned long long*)(ws + OFF_SELKEY);
  float* sel_sc               = (float*)(ws + OFF_SELSC);
  float* sel_box              = (float*)(ws + OFF_SELBOX);
  unsigned long long* maskbuf = (unsigned long long*)(ws + OFF_MASK);
  unsigned long long* ckey    = (unsigned long long*)(ws + OFF_CKEY);  // aliases maskbuf (dead before k_masks)
  unsigned long long* keep    = (unsigned long long*)(ws + OFF_KEEP);
  float* out                  = (float*)d_out;

  hipMemsetAsync(d_ws, 0, ZERO_BYTES, stream);                 // hist + counters + thr
  hipMemsetAsync(d_out, 0, (size_t)NIMG*OUTK*5*sizeof(float), stream); // zero-padded outputs

  k_hist   <<<NIMG*BLK_PER_IMG, 256, 0, stream>>>(in, hist);
  k_scan   <<<NPAIR, 256, 0, stream>>>(hist, thr);
  k_compact<<<NIMG*BLK_PER_IMG, 256, 0, stream>>>(in, thr, cnt, cand);
  k_keys   <<<dim3(CAP/256, NPAIR), 256, 0, stream>>>(in, cnt, cand, ckey);
  k_rank   <<<dim3(CAP/256, NPAIR), 256, 0, stream>>>(cnt, cand, ckey, sel_idx, sel_key, sel_sc);
  k_decode <<<(NIMG*MTOT + 255)/256, 256, 0, stream>>>(in, sel_idx, sel_box);
  k_masks  <<<dim3(64, NPAIR), 256, 0, stream>>>(sel_box, maskbuf);
  k_nms    <<<NPAIR, 64, 0, stream>>>(maskbuf, keep);
  k_pfx    <<<NPAIR, 64, 0, stream>>>(keep, pkc);
  k_out2   <<<dim3((MTOT + 255)/256, NIMG), 256, 0, stream>>>(sel_key, sel_box, keep, pkc, out);
}